// Round 8
// baseline (119.991 us; speedup 1.0000x reference)
//
#include <hip/hip_runtime.h>

// GroupAvgPool1d: x [B,N,C] fp32, y [B,N] int group ids, G groups.
// d_out = feature [B,G,C] fp32 ++ mask [B,G] (0.0/1.0).
// Shapes fixed: B=16, N=8192, C=64, G=512.
//
// v8: streaming scatter, fixed. Phase1: 256 blocks (1/CU), block (b,h,cs)
// streams rows [h*2048,+2048) x channels [cs*16,+16) — every 64B line read
// exactly once, sequential-order aggregate -> full HBM BW — and ds_add's
// into a 50KB LDS [G][25] accumulator (odd stride: conflict-free banks).
// Partials [256][512][16] = 8MB. Phase2: reduce 4 partials/elem + mask.

#define B_ 16
#define N_ 8192
#define C_ 64
#define G_ 512
#define H_ 4              // row quarters per batch
#define ROWS 2048         // N_/H_
#define CS_ 4             // channel slices (16 ch = one 64B line each)
#define CW 16
#define STR 25            // odd LDS stride (floats) -> ds_add banks spread

__global__ __launch_bounds__(512)
void gap8_p1(const float* __restrict__ x, const int* __restrict__ y,
             float* __restrict__ pfeat, int* __restrict__ pcnt) {
    const int t   = threadIdx.x;          // 0..511
    const int blk = blockIdx.x;           // ((b*H_+h)*CS_+cs)
    const int cs  = blk & 3;
    const int h   = (blk >> 2) & 3;
    const int b   = blk >> 4;

    __shared__ float lacc[G_ * STR];      // 50 KB
    __shared__ int   sy[ROWS];            // 8 KB
    __shared__ int   lcnt[G_];            // 2 KB

    for (int i = t; i < G_ * STR; i += 512) lacc[i] = 0.f;
    for (int i = t; i < G_; i += 512) lcnt[i] = 0;
    const int4 yv = *reinterpret_cast<const int4*>(y + b * N_ + h * ROWS + t * 4);
    *reinterpret_cast<int4*>(&sy[t * 4]) = yv;
    __syncthreads();

    if (cs == 0) {                        // member counts (one block per (b,h))
        if ((unsigned)yv.x < G_) atomicAdd(&lcnt[yv.x], 1);
        if ((unsigned)yv.y < G_) atomicAdd(&lcnt[yv.y], 1);
        if ((unsigned)yv.z < G_) atomicAdd(&lcnt[yv.z], 1);
        if ((unsigned)yv.w < G_) atomicAdd(&lcnt[yv.w], 1);
    }

    // x stream: thread -> (row = base + t>>2, k = t&3); 16 float4/thread in
    // two MLP=8 batches. Wave covers 16 rows x 64B contiguous chunks.
    const float* xb = x + ((size_t)b * N_ + (size_t)h * ROWS) * C_ + cs * CW;
    const int k  = t & 3;
    const int rt = t >> 2;                // 0..127

    #pragma unroll
    for (int half = 0; half < 2; ++half) {
        float4 v[8]; int g[8];
        #pragma unroll
        for (int r8 = 0; r8 < 8; ++r8) {  // 8 independent 16B loads
            const int row = half * 1024 + r8 * 128 + rt;
            v[r8] = *reinterpret_cast<const float4*>(xb + (size_t)row * C_ + k * 4);
        }
        #pragma unroll
        for (int r8 = 0; r8 < 8; ++r8)
            g[r8] = sy[half * 1024 + r8 * 128 + rt];   // broadcast-friendly
        #pragma unroll
        for (int r8 = 0; r8 < 8; ++r8) {
            const unsigned gi = (unsigned)g[r8];       // y<0 -> huge -> skip
            if (gi < G_) {
                float* p = &lacc[gi * STR + k * 4];
                atomicAdd(p + 0, v[r8].x);
                atomicAdd(p + 1, v[r8].y);
                atomicAdd(p + 2, v[r8].z);
                atomicAdd(p + 3, v[r8].w);
            }
        }
    }
    __syncthreads();

    // writeout: pfeat[blk][g][16], coalesced scalar stores
    float* pf = pfeat + (size_t)blk * (G_ * CW);
    #pragma unroll
    for (int r = 0; r < 16; ++r) {
        const int i = r * 512 + t;        // 0..8191
        pf[i] = lacc[(i >> 4) * STR + (i & 15)];
    }
    if (cs == 0)
        for (int i = t; i < G_; i += 512)
            pcnt[(b * H_ + h) * G_ + i] = lcnt[i];
}

__global__ __launch_bounds__(256)
void gap8_p2(const float* __restrict__ pfeat, const int* __restrict__ pcnt,
             float* __restrict__ feature, float* __restrict__ maskout) {
    const int f = blockIdx.x * 256 + threadIdx.x;
    if (f < B_ * G_ * C_) {
        const int b   = f >> 15;
        const int g   = (f >> 6) & (G_ - 1);
        const int c   = f & (C_ - 1);
        const int cs  = c >> 4;
        const int c16 = c & 15;
        float sum = 0.f;
        #pragma unroll
        for (int h = 0; h < H_; ++h)
            sum += pfeat[((size_t)((b * H_ + h) * CS_ + cs) * G_ + g) * CW + c16];
        feature[f] = sum * (1.0f / (float)N_);
    } else {
        const int m = f - B_ * G_ * C_;   // 0..B_*G_-1 (grid sized exactly)
        const int b = m >> 9;
        const int g = m & (G_ - 1);
        int c = 0;
        #pragma unroll
        for (int h = 0; h < H_; ++h)
            c += pcnt[(b * H_ + h) * G_ + g];
        maskout[m] = (c > 0) ? 1.0f : 0.0f;
    }
}

extern "C" void kernel_launch(void* const* d_in, const int* in_sizes, int n_in,
                              void* d_out, int out_size, void* d_ws, size_t ws_size,
                              hipStream_t stream) {
    const float* x = (const float*)d_in[0];
    const int*   y = (const int*)d_in[1];
    float* feature = (float*)d_out;                        // B*G*C floats
    float* maskout = feature + (size_t)B_ * G_ * C_;       // B*G floats
    float* pfeat   = (float*)d_ws;                         // [256][512][16] = 8 MB
    int*   pcnt    = (int*)(pfeat + (size_t)256 * G_ * CW);// [64][512] = 128 KB

    gap8_p1<<<B_ * H_ * CS_, 512, 0, stream>>>(x, y, pfeat, pcnt);

    const int total = B_ * G_ * C_ + B_ * G_;              // 532480 = 2080*256
    gap8_p2<<<total / 256, 256, 0, stream>>>(pfeat, pcnt, feature, maskout);
}